// Round 2
// baseline (4437.926 us; speedup 1.0000x reference)
//
#include <hip/hip_runtime.h>
#include <cstdint>
#include <cstddef>

#define BATCH   512
#define HIDDEN  512
#define EMB     512
#define VOCAB   4096
#define NOBJ    3
#define FEATIN  2048
#define FEATSZ  512
#define MAXLEN  40
#define TSTEPS  38
#define SOS     1
#define EOS     2

// GEMM tile: C[M,N] = A[M,K] @ B[N,K]^T. 64x64 tile, BK=16, 128 threads (2 waves),
// 4x8 micro-tile per thread. LDS rows padded +4 floats: keeps 16B alignment for
// ds_read_b128 (stride 272B) and makes every LDS access pattern <=2-way (free).
#define BM 64
#define BN 64
#define BK 16
#define GTHREADS 128

static __device__ __forceinline__ unsigned long long pack_key(float v, int col) {
    uint32_t u = __float_as_uint(v);
    u = (u & 0x80000000u) ? ~u : (u | 0x80000000u);   // order-preserving map
    return ((unsigned long long)u << 32) | (uint32_t)(VOCAB - 1 - col);  // low col wins ties
}

// ---------------- zero d_out + keys (replaces slow rocclr fill)
__global__ __launch_bounds__(256) void k_zero(float* __restrict__ out, int n,
                                              unsigned long long* __restrict__ keys) {
    size_t i = (size_t)blockIdx.x * 256 + threadIdx.x;
    size_t i4 = i * 4;
    if (i4 + 3 < (size_t)n) {
        *(float4*)&out[i4] = make_float4(0.f, 0.f, 0.f, 0.f);
    } else if (i4 < (size_t)n) {
        for (size_t j = i4; j < (size_t)n; ++j) out[j] = 0.f;
    }
    if (i < (size_t)TSTEPS * BATCH) keys[i] = 0ULL;
}

#define STAGE_A() do { \
    As[lk+0][lrow]=a0.x; As[lk+1][lrow]=a0.y; As[lk+2][lrow]=a0.z; As[lk+3][lrow]=a0.w; \
    As[lk+4][lrow]=a1.x; As[lk+5][lrow]=a1.y; As[lk+6][lrow]=a1.z; As[lk+7][lrow]=a1.w; } while(0)
#define STAGE_B() do { \
    Bs[lk+0][lrow]=b0.x; Bs[lk+1][lrow]=b0.y; Bs[lk+2][lrow]=b0.z; Bs[lk+3][lrow]=b0.w; \
    Bs[lk+4][lrow]=b1.x; Bs[lk+5][lrow]=b1.y; Bs[lk+6][lrow]=b1.z; Bs[lk+7][lrow]=b1.w; } while(0)
#define COMPUTE16() do { \
    _Pragma("unroll") \
    for (int kk = 0; kk < BK; ++kk) { \
        float4 av  = *(const float4*)&As[kk][ty * 4]; \
        float4 bv0 = *(const float4*)&Bs[kk][tx * 8]; \
        float4 bv1 = *(const float4*)&Bs[kk][tx * 8 + 4]; \
        float ar[4] = {av.x, av.y, av.z, av.w}; \
        float br[8] = {bv0.x, bv0.y, bv0.z, bv0.w, bv1.x, bv1.y, bv1.z, bv1.w}; \
        _Pragma("unroll") \
        for (int i = 0; i < 4; ++i) \
            _Pragma("unroll") \
            for (int j = 0; j < 8; ++j) acc[i][j] += ar[i] * br[j]; \
    } } while(0)

// ---------------- feature embed: fe[1536,512] = feats[1536,2048] @ featW[512,2048]^T + featb
__global__ __launch_bounds__(GTHREADS) void k_fe(const float* __restrict__ feats,
                                                 const float* __restrict__ featW,
                                                 const float* __restrict__ featb,
                                                 float* __restrict__ fe) {
    __shared__ __align__(16) float As[BK][BM + 4];
    __shared__ __align__(16) float Bs[BK][BN + 4];
    const int tid = threadIdx.x;
    const int tx = tid & 7, ty = tid >> 3;
    const int lrow = tid >> 1, lk = (tid & 1) * 8;
    const int m0 = blockIdx.y * BM, n0 = blockIdx.x * BN;
    const float* Ap = feats + (size_t)(m0 + lrow) * FEATIN;
    const float* Bp = featW + (size_t)(n0 + lrow) * FEATIN;
    float acc[4][8] = {};
    float4 a0 = *(const float4*)&Ap[lk], a1 = *(const float4*)&Ap[lk + 4];
    float4 b0 = *(const float4*)&Bp[lk], b1 = *(const float4*)&Bp[lk + 4];
    for (int k0 = 0; k0 < FEATIN; k0 += BK) {
        if (k0) __syncthreads();
        STAGE_A(); STAGE_B();
        __syncthreads();
        if (k0 + BK < FEATIN) {
            a0 = *(const float4*)&Ap[k0 + BK + lk]; a1 = *(const float4*)&Ap[k0 + BK + lk + 4];
            b0 = *(const float4*)&Bp[k0 + BK + lk]; b1 = *(const float4*)&Bp[k0 + BK + lk + 4];
        }
        COMPUTE16();
    }
#pragma unroll
    for (int i = 0; i < 4; ++i) {
        int r = m0 + ty * 4 + i, c0 = n0 + tx * 8;
        float4 o0 = make_float4(acc[i][0] + featb[c0+0], acc[i][1] + featb[c0+1],
                                acc[i][2] + featb[c0+2], acc[i][3] + featb[c0+3]);
        float4 o1 = make_float4(acc[i][4] + featb[c0+4], acc[i][5] + featb[c0+5],
                                acc[i][6] + featb[c0+6], acc[i][7] + featb[c0+7]);
        *(float4*)&fe[(size_t)r * FEATSZ + c0] = o0;
        *(float4*)&fe[(size_t)r * FEATSZ + c0 + 4] = o1;
    }
}

// ---------------- h0[512,512] = ft[512,1539] @ initW[512,1539]^T + initb
// GEMM over the 1536 fe columns (initW col remap ka -> ka + ka/512); one-hot term in epilogue.
__global__ __launch_bounds__(GTHREADS) void k_h0(const float* __restrict__ fe,
                                                 const float* __restrict__ initW,
                                                 const float* __restrict__ initb,
                                                 const int* __restrict__ targets,
                                                 float* __restrict__ h) {
    __shared__ __align__(16) float As[BK][BM + 4];
    __shared__ __align__(16) float Bs[BK][BN + 4];
    const int tid = threadIdx.x;
    const int tx = tid & 7, ty = tid >> 3;
    const int lrow = tid >> 1, lk = (tid & 1) * 8;
    const int m0 = blockIdx.y * BM, n0 = blockIdx.x * BN;
    const int K = NOBJ * FEATSZ;  // 1536
    const float* Ap = fe + (size_t)(m0 + lrow) * K;
    const float* Bp = initW + (size_t)(n0 + lrow) * 1539;
    float acc[4][8] = {};
    float4 a0 = *(const float4*)&Ap[lk], a1 = *(const float4*)&Ap[lk + 4];
    float br8[8];
#pragma unroll
    for (int i = 0; i < 8; ++i) { int ka = lk + i; br8[i] = Bp[ka + (ka >> 9)]; }
    for (int k0 = 0; k0 < K; k0 += BK) {
        if (k0) __syncthreads();
        STAGE_A();
#pragma unroll
        for (int i = 0; i < 8; ++i) Bs[lk + i][lrow] = br8[i];
        __syncthreads();
        if (k0 + BK < K) {
            a0 = *(const float4*)&Ap[k0 + BK + lk]; a1 = *(const float4*)&Ap[k0 + BK + lk + 4];
#pragma unroll
            for (int i = 0; i < 8; ++i) { int ka = k0 + BK + lk + i; br8[i] = Bp[ka + (ka >> 9)]; }
        }
        COMPUTE16();
    }
#pragma unroll
    for (int i = 0; i < 4; ++i) {
        int r = m0 + ty * 4 + i, c0 = n0 + tx * 8;
        int tg = targets[r];
#pragma unroll
        for (int j = 0; j < 8; ++j) {
            int c = c0 + j;
            h[(size_t)r * HIDDEN + c] =
                acc[i][j] + initb[c] + initW[(size_t)c * 1539 + tg * 513 + 512];
        }
    }
}

// ---------------- gates: G[512,3072]: cols [0,1536) = emb_W[pred]@Wih^T + bih,
// cols [1536,3072) = h@Whh^T + bhh
__global__ __launch_bounds__(GTHREADS) void k_gates(const float* __restrict__ embW,
                                                    const float* __restrict__ h,
                                                    const float* __restrict__ Wih,
                                                    const float* __restrict__ Whh,
                                                    const float* __restrict__ bih,
                                                    const float* __restrict__ bhh,
                                                    const unsigned long long* __restrict__ keys_prev,
                                                    float* __restrict__ G) {
    __shared__ __align__(16) float As[BK][BM + 4];
    __shared__ __align__(16) float Bs[BK][BN + 4];
    const int tid = threadIdx.x;
    const int tx = tid & 7, ty = tid >> 3;
    const int lrow = tid >> 1, lk = (tid & 1) * 8;
    const int m0 = blockIdx.y * BM;
    const int n0g = blockIdx.x * BN;
    const bool hhalf = (n0g >= 3 * HIDDEN);
    const float* Ap;
    if (!hhalf) {
        int tok = SOS;
        if (keys_prev)
            tok = (VOCAB - 1) - (int)(uint32_t)(keys_prev[m0 + lrow] & 0xffffffffULL);
        Ap = embW + (size_t)tok * EMB;
    } else {
        Ap = h + (size_t)(m0 + lrow) * HIDDEN;
    }
    const float* Bp = hhalf ? (Whh + (size_t)(n0g - 3 * HIDDEN + lrow) * HIDDEN)
                            : (Wih + (size_t)(n0g + lrow) * EMB);
    float acc[4][8] = {};
    float4 a0 = *(const float4*)&Ap[lk], a1 = *(const float4*)&Ap[lk + 4];
    float4 b0 = *(const float4*)&Bp[lk], b1 = *(const float4*)&Bp[lk + 4];
    for (int k0 = 0; k0 < HIDDEN; k0 += BK) {
        if (k0) __syncthreads();
        STAGE_A(); STAGE_B();
        __syncthreads();
        if (k0 + BK < HIDDEN) {
            a0 = *(const float4*)&Ap[k0 + BK + lk]; a1 = *(const float4*)&Ap[k0 + BK + lk + 4];
            b0 = *(const float4*)&Bp[k0 + BK + lk]; b1 = *(const float4*)&Bp[k0 + BK + lk + 4];
        }
        COMPUTE16();
    }
    const float* bias = hhalf ? bhh : bih;
    const int nb = hhalf ? (n0g - 3 * HIDDEN) : n0g;
#pragma unroll
    for (int i = 0; i < 4; ++i) {
        int r = m0 + ty * 4 + i, c0 = tx * 8;
        float4 o0 = make_float4(acc[i][0] + bias[nb+c0+0], acc[i][1] + bias[nb+c0+1],
                                acc[i][2] + bias[nb+c0+2], acc[i][3] + bias[nb+c0+3]);
        float4 o1 = make_float4(acc[i][4] + bias[nb+c0+4], acc[i][5] + bias[nb+c0+5],
                                acc[i][6] + bias[nb+c0+6], acc[i][7] + bias[nb+c0+7]);
        *(float4*)&G[(size_t)r * (6 * HIDDEN) + n0g + c0] = o0;
        *(float4*)&G[(size_t)r * (6 * HIDDEN) + n0g + c0 + 4] = o1;
    }
}

// ---------------- GRU elementwise: h = (1-z)*n + z*h
__global__ __launch_bounds__(256) void k_gru(const float* __restrict__ G,
                                             float* __restrict__ h) {
    int idx = blockIdx.x * 256 + threadIdx.x;
    int b = idx >> 9, j = idx & (HIDDEN - 1);
    const float* g = G + (size_t)b * (6 * HIDDEN);
    float ir = g[j], iz = g[j + HIDDEN], inn = g[j + 2 * HIDDEN];
    float hr = g[j + 3 * HIDDEN], hz = g[j + 4 * HIDDEN], hn = g[j + 5 * HIDDEN];
    float r = 1.0f / (1.0f + expf(-(ir + hr)));
    float z = 1.0f / (1.0f + expf(-(iz + hz)));
    float n = tanhf(inn + r * hn);
    float ho = h[idx];
    h[idx] = (1.0f - z) * n + z * ho;
}

// ---------------- logits + argmax: per-row max over V of pack(logit + outb + gumbel)
__global__ __launch_bounds__(GTHREADS) void k_logits(const float* __restrict__ h,
                                                     const float* __restrict__ outW,
                                                     const float* __restrict__ outb,
                                                     const float* __restrict__ gum_t,
                                                     unsigned long long* __restrict__ keys_t) {
    __shared__ __align__(16) float As[BK][BM + 4];
    __shared__ __align__(16) float Bs[BK][BN + 4];
    __shared__ unsigned long long red[BM][8];
    const int tid = threadIdx.x;
    const int tx = tid & 7, ty = tid >> 3;
    const int lrow = tid >> 1, lk = (tid & 1) * 8;
    const int m0 = blockIdx.y * BM, n0 = blockIdx.x * BN;
    const float* Ap = h + (size_t)(m0 + lrow) * HIDDEN;
    const float* Bp = outW + (size_t)(n0 + lrow) * HIDDEN;
    float acc[4][8] = {};
    float4 a0 = *(const float4*)&Ap[lk], a1 = *(const float4*)&Ap[lk + 4];
    float4 b0 = *(const float4*)&Bp[lk], b1 = *(const float4*)&Bp[lk + 4];
    for (int k0 = 0; k0 < HIDDEN; k0 += BK) {
        if (k0) __syncthreads();
        STAGE_A(); STAGE_B();
        __syncthreads();
        if (k0 + BK < HIDDEN) {
            a0 = *(const float4*)&Ap[k0 + BK + lk]; a1 = *(const float4*)&Ap[k0 + BK + lk + 4];
            b0 = *(const float4*)&Bp[k0 + BK + lk]; b1 = *(const float4*)&Bp[k0 + BK + lk + 4];
        }
        COMPUTE16();
    }
#pragma unroll
    for (int i = 0; i < 4; ++i) {
        int r = m0 + ty * 4 + i, c0 = n0 + tx * 8;
        unsigned long long best = 0ULL;
#pragma unroll
        for (int j = 0; j < 8; ++j) {
            int c = c0 + j;
            float v = acc[i][j] + outb[c] + gum_t[(size_t)r * VOCAB + c];
            unsigned long long key = pack_key(v, c);
            if (key > best) best = key;
        }
        red[ty * 4 + i][tx] = best;
    }
    __syncthreads();
    if (tid < BM) {
        unsigned long long best = red[tid][0];
#pragma unroll
        for (int q = 1; q < 8; ++q)
            if (red[tid][q] > best) best = red[tid][q];
        atomicMax(&keys_t[m0 + tid], best);
    }
}

// ---------------- finalize: tokens -> lengths -> scatter one-hots + length + eos_loss
__global__ __launch_bounds__(256) void k_final(const unsigned long long* __restrict__ keys,
                                               float* __restrict__ out) {
    int b = blockIdx.x * 256 + threadIdx.x;
    if (b >= BATCH) return;
    int toks[TSTEPS];
    int len = 1;
    bool done = false;
#pragma unroll
    for (int t = 0; t < TSTEPS; ++t) {
        int tok = (VOCAB - 1) - (int)(uint32_t)(keys[(size_t)t * BATCH + b] & 0xffffffffULL);
        toks[t] = tok;
        if (!done) len++;
        if (tok == EOS) done = true;
    }
    if (!done) len++;
    float* lang = out + (size_t)b * MAXLEN * VOCAB;
    lang[SOS] = 1.0f;
#pragma unroll
    for (int t = 0; t < TSTEPS; ++t) {
        int pos = t + 1;
        if (pos < len) lang[(size_t)pos * VOCAB + toks[t]] = 1.0f;
    }
    if (len == MAXLEN) lang[(size_t)(MAXLEN - 1) * VOCAB + EOS] = 1.0f;
    out[(size_t)BATCH * MAXLEN * VOCAB + b] = (float)len;
    if (b == 0) out[(size_t)BATCH * MAXLEN * VOCAB + BATCH] = 0.0f;
}

extern "C" void kernel_launch(void* const* d_in, const int* in_sizes, int n_in,
                              void* d_out, int out_size, void* d_ws, size_t ws_size,
                              hipStream_t stream) {
    const float* feats = (const float*)d_in[0];
    const int*   targets = (const int*)d_in[1];
    const float* featW = (const float*)d_in[2];
    const float* featb = (const float*)d_in[3];
    const float* embW  = (const float*)d_in[4];
    const float* initW = (const float*)d_in[5];
    const float* initb = (const float*)d_in[6];
    const float* Wih   = (const float*)d_in[7];
    const float* Whh   = (const float*)d_in[8];
    const float* bih   = (const float*)d_in[9];
    const float* bhh   = (const float*)d_in[10];
    const float* outW  = (const float*)d_in[11];
    const float* outb  = (const float*)d_in[12];
    const float* gumbel = (const float*)d_in[13];
    float* out = (float*)d_out;

    char* ws = (char*)d_ws;
    float* h  = (float*)(ws);                                   // 1 MB
    float* G  = (float*)(ws + (1 << 20));                       // 6 MB
    float* fe = (float*)(ws + 7 * (1 << 20));                   // 3 MB
    unsigned long long* keys = (unsigned long long*)(ws + 10 * (1 << 20));  // 152 KB

    int zb = (out_size / 4 + 256) / 256;
    k_zero<<<dim3(zb), 256, 0, stream>>>(out, out_size, keys);

    k_fe<<<dim3(FEATSZ / BN, (BATCH * NOBJ) / BM), GTHREADS, 0, stream>>>(feats, featW, featb, fe);
    k_h0<<<dim3(HIDDEN / BN, BATCH / BM), GTHREADS, 0, stream>>>(fe, initW, initb, targets, h);

    for (int t = 0; t < TSTEPS; ++t) {
        const unsigned long long* kprev = (t == 0) ? nullptr : (keys + (size_t)(t - 1) * BATCH);
        k_gates<<<dim3((6 * HIDDEN) / BN, BATCH / BM), GTHREADS, 0, stream>>>(
            embW, h, Wih, Whh, bih, bhh, kprev, G);
        k_gru<<<dim3((BATCH * HIDDEN) / 256), 256, 0, stream>>>(G, h);
        k_logits<<<dim3(VOCAB / BN, BATCH / BM), GTHREADS, 0, stream>>>(
            h, outW, outb, gumbel + (size_t)t * BATCH * VOCAB, keys + (size_t)t * BATCH);
    }
    k_final<<<dim3(2), 256, 0, stream>>>(keys, out);
}

// Round 3
// 3204.406 us; speedup vs baseline: 1.3849x; 1.3849x over previous
//
#include <hip/hip_runtime.h>
#include <cstdint>
#include <cstddef>

#define BATCH   512
#define HIDDEN  512
#define EMB     512
#define VOCAB   4096
#define NOBJ    3
#define FEATIN  2048
#define FEATSZ  512
#define MAXLEN  40
#define TSTEPS  38
#define SOS     1
#define EOS     2
#define GIH     1536   // 3*HIDDEN

#define BK 16
#define BM 64

static __device__ __forceinline__ unsigned long long pack_key(float v, int col) {
    uint32_t u = __float_as_uint(v);
    u = (u & 0x80000000u) ? ~u : (u | 0x80000000u);   // order-preserving map
    return ((unsigned long long)u << 32) | (uint32_t)(VOCAB - 1 - col);  // low col wins ties
}

// ---------------- zero d_out + keys
__global__ __launch_bounds__(256) void k_zero(float* __restrict__ out, int n,
                                              unsigned long long* __restrict__ keys) {
    size_t i = (size_t)blockIdx.x * 256 + threadIdx.x;
    size_t i4 = i * 4;
    if (i4 + 3 < (size_t)n) {
        *(float4*)&out[i4] = make_float4(0.f, 0.f, 0.f, 0.f);
    } else if (i4 < (size_t)n) {
        for (size_t j = i4; j < (size_t)n; ++j) out[j] = 0.f;
    }
    if (i < (size_t)TSTEPS * BATCH) keys[i] = 0ULL;
}

// ---------------- feature embed (one-time, R1 structure): fe[1536,512] = feats @ featW^T + featb
__global__ __launch_bounds__(256) void k_fe(const float* __restrict__ feats,
                                            const float* __restrict__ featW,
                                            const float* __restrict__ featb,
                                            float* __restrict__ fe) {
    __shared__ float As[BK][BM];
    __shared__ float Bs[BK][BM];
    const int tid = threadIdx.x;
    const int m0 = blockIdx.y * BM, n0 = blockIdx.x * BM;
    const int tx = tid & 15, ty = tid >> 4;
    const int lrow = tid >> 2, lk = (tid & 3) << 2;
    float acc[4][4] = {};
    for (int k0 = 0; k0 < FEATIN; k0 += BK) {
        float4 a = *(const float4*)&feats[(size_t)(m0 + lrow) * FEATIN + k0 + lk];
        float4 b = *(const float4*)&featW[(size_t)(n0 + lrow) * FEATIN + k0 + lk];
        __syncthreads();
        As[lk+0][lrow] = a.x; As[lk+1][lrow] = a.y; As[lk+2][lrow] = a.z; As[lk+3][lrow] = a.w;
        Bs[lk+0][lrow] = b.x; Bs[lk+1][lrow] = b.y; Bs[lk+2][lrow] = b.z; Bs[lk+3][lrow] = b.w;
        __syncthreads();
#pragma unroll
        for (int kk = 0; kk < BK; ++kk) {
            float4 av = *(const float4*)&As[kk][ty * 4];
            float4 bv = *(const float4*)&Bs[kk][tx * 4];
            float ar[4] = {av.x, av.y, av.z, av.w};
            float br[4] = {bv.x, bv.y, bv.z, bv.w};
#pragma unroll
            for (int i = 0; i < 4; ++i)
#pragma unroll
                for (int j = 0; j < 4; ++j) acc[i][j] += ar[i] * br[j];
        }
    }
#pragma unroll
    for (int i = 0; i < 4; ++i) {
        int r = m0 + ty * 4 + i;
#pragma unroll
        for (int j = 0; j < 4; ++j) {
            int c = n0 + tx * 4 + j;
            fe[(size_t)r * FEATSZ + c] = acc[i][j] + featb[c];
        }
    }
}

// ---------------- h0 (one-time, R1 structure): h0 = ft[512,1539] @ initW^T + initb
__global__ __launch_bounds__(256) void k_h0(const float* __restrict__ fe,
                                            const float* __restrict__ initW,
                                            const float* __restrict__ initb,
                                            const int* __restrict__ targets,
                                            float* __restrict__ h) {
    __shared__ float As[BK][BM];
    __shared__ float Bs[BK][BM];
    const int tid = threadIdx.x;
    const int m0 = blockIdx.y * BM, n0 = blockIdx.x * BM;
    const int tx = tid & 15, ty = tid >> 4;
    const int lrow = tid >> 2, lk = (tid & 3) << 2;
    float acc[4][4] = {};
    const int K = NOBJ * FEATSZ;  // 1536
    for (int k0 = 0; k0 < K; k0 += BK) {
        float4 a = *(const float4*)&fe[(size_t)(m0 + lrow) * K + k0 + lk];
        float breg[4];
#pragma unroll
        for (int i = 0; i < 4; ++i) {
            int ka = k0 + lk + i;
            breg[i] = initW[(size_t)(n0 + lrow) * 1539 + ka + (ka >> 9)];
        }
        __syncthreads();
        As[lk+0][lrow] = a.x; As[lk+1][lrow] = a.y; As[lk+2][lrow] = a.z; As[lk+3][lrow] = a.w;
#pragma unroll
        for (int i = 0; i < 4; ++i) Bs[lk + i][lrow] = breg[i];
        __syncthreads();
#pragma unroll
        for (int kk = 0; kk < BK; ++kk) {
            float4 av = *(const float4*)&As[kk][ty * 4];
            float4 bv = *(const float4*)&Bs[kk][tx * 4];
            float ar[4] = {av.x, av.y, av.z, av.w};
            float br[4] = {bv.x, bv.y, bv.z, bv.w};
#pragma unroll
            for (int i = 0; i < 4; ++i)
#pragma unroll
                for (int j = 0; j < 4; ++j) acc[i][j] += ar[i] * br[j];
        }
    }
#pragma unroll
    for (int i = 0; i < 4; ++i) {
        int r = m0 + ty * 4 + i;
        int tg = targets[r];
#pragma unroll
        for (int j = 0; j < 4; ++j) {
            int c = n0 + tx * 4 + j;
            h[(size_t)r * HIDDEN + c] =
                acc[i][j] + initb[c] + initW[(size_t)c * 1539 + tg * 513 + 512];
        }
    }
}

// ---------------- P[4096,1536] = embW[4096,512] @ Wih[1536,512]^T  (one-time)
// 256 thr, BM=64 x BN=128, 4x8 micro, double-buffered LDS, 1 barrier/iter.
__global__ __launch_bounds__(256) void k_P(const float* __restrict__ embW,
                                           const float* __restrict__ Wih,
                                           float* __restrict__ P) {
    __shared__ __align__(16) float As[2][BK][BM + 4];
    __shared__ __align__(16) float Bs[2][BK][128 + 4];
    const int tid = threadIdx.x;
    const int arow = tid >> 2, ak = (tid & 3) << 2;
    const int tx = tid & 15, ty = tid >> 4;
    const int m0 = blockIdx.y * BM, n0 = blockIdx.x * 128;
    const float* Ap = embW + (size_t)(m0 + arow) * EMB;
    const float* Bp0 = Wih + (size_t)(n0 + arow) * EMB;
    const float* Bp1 = Wih + (size_t)(n0 + 64 + arow) * EMB;
    float4 aR = *(const float4*)&Ap[ak];
    float4 bR0 = *(const float4*)&Bp0[ak];
    float4 bR1 = *(const float4*)&Bp1[ak];
    float acc[4][8] = {};
    int buf = 0;
    for (int k0 = 0; k0 < EMB; k0 += BK) {
        As[buf][ak+0][arow] = aR.x; As[buf][ak+1][arow] = aR.y;
        As[buf][ak+2][arow] = aR.z; As[buf][ak+3][arow] = aR.w;
        Bs[buf][ak+0][arow] = bR0.x; Bs[buf][ak+1][arow] = bR0.y;
        Bs[buf][ak+2][arow] = bR0.z; Bs[buf][ak+3][arow] = bR0.w;
        Bs[buf][ak+0][arow+64] = bR1.x; Bs[buf][ak+1][arow+64] = bR1.y;
        Bs[buf][ak+2][arow+64] = bR1.z; Bs[buf][ak+3][arow+64] = bR1.w;
        __syncthreads();
        if (k0 + BK < EMB) {
            aR  = *(const float4*)&Ap[k0 + BK + ak];
            bR0 = *(const float4*)&Bp0[k0 + BK + ak];
            bR1 = *(const float4*)&Bp1[k0 + BK + ak];
        }
#pragma unroll
        for (int kk = 0; kk < BK; ++kk) {
            float4 av  = *(const float4*)&As[buf][kk][ty * 4];
            float4 bv0 = *(const float4*)&Bs[buf][kk][tx * 4];
            float4 bv1 = *(const float4*)&Bs[buf][kk][64 + tx * 4];
            float ar[4] = {av.x, av.y, av.z, av.w};
            float br[8] = {bv0.x, bv0.y, bv0.z, bv0.w, bv1.x, bv1.y, bv1.z, bv1.w};
#pragma unroll
            for (int i = 0; i < 4; ++i)
#pragma unroll
                for (int j = 0; j < 8; ++j) acc[i][j] += ar[i] * br[j];
        }
        buf ^= 1;
    }
#pragma unroll
    for (int i = 0; i < 4; ++i) {
        int r = m0 + ty * 4 + i;
        *(float4*)&P[(size_t)r * GIH + n0 + tx * 4] =
            make_float4(acc[i][0], acc[i][1], acc[i][2], acc[i][3]);
        *(float4*)&P[(size_t)r * GIH + n0 + 64 + tx * 4] =
            make_float4(acc[i][4], acc[i][5], acc[i][6], acc[i][7]);
    }
}

// ---------------- Gh[512,1536] = h[512,512] @ Whh[1536,512]^T  (per step, no bias)
__global__ __launch_bounds__(256) void k_gatesH(const float* __restrict__ h,
                                                const float* __restrict__ Whh,
                                                float* __restrict__ Gh) {
    __shared__ __align__(16) float As[2][BK][BM + 4];
    __shared__ __align__(16) float Bs[2][BK][BM + 4];
    const int tid = threadIdx.x;
    const int arow = tid >> 2, ak = (tid & 3) << 2;
    const int tx = tid & 15, ty = tid >> 4;
    const int m0 = blockIdx.y * BM, n0 = blockIdx.x * BM;
    const float* Ap = h + (size_t)(m0 + arow) * HIDDEN;
    const float* Bp = Whh + (size_t)(n0 + arow) * HIDDEN;
    float4 aR = *(const float4*)&Ap[ak];
    float4 bR = *(const float4*)&Bp[ak];
    float acc[4][4] = {};
    int buf = 0;
    for (int k0 = 0; k0 < HIDDEN; k0 += BK) {
        As[buf][ak+0][arow] = aR.x; As[buf][ak+1][arow] = aR.y;
        As[buf][ak+2][arow] = aR.z; As[buf][ak+3][arow] = aR.w;
        Bs[buf][ak+0][arow] = bR.x; Bs[buf][ak+1][arow] = bR.y;
        Bs[buf][ak+2][arow] = bR.z; Bs[buf][ak+3][arow] = bR.w;
        __syncthreads();
        if (k0 + BK < HIDDEN) {
            aR = *(const float4*)&Ap[k0 + BK + ak];
            bR = *(const float4*)&Bp[k0 + BK + ak];
        }
#pragma unroll
        for (int kk = 0; kk < BK; ++kk) {
            float4 av = *(const float4*)&As[buf][kk][ty * 4];
            float4 bv = *(const float4*)&Bs[buf][kk][tx * 4];
            float ar[4] = {av.x, av.y, av.z, av.w};
            float br[4] = {bv.x, bv.y, bv.z, bv.w};
#pragma unroll
            for (int i = 0; i < 4; ++i)
#pragma unroll
                for (int j = 0; j < 4; ++j) acc[i][j] += ar[i] * br[j];
        }
        buf ^= 1;
    }
#pragma unroll
    for (int i = 0; i < 4; ++i) {
        int r = m0 + ty * 4 + i;
        *(float4*)&Gh[(size_t)r * GIH + n0 + tx * 4] =
            make_float4(acc[i][0], acc[i][1], acc[i][2], acc[i][3]);
    }
}

// ---------------- GRU elementwise: h = (1-z)*n + z*h, with i-gates gathered from P[tok]
__global__ __launch_bounds__(256) void k_gru(const float* __restrict__ Gh,
                                             const float* __restrict__ P,
                                             const float* __restrict__ bih,
                                             const float* __restrict__ bhh,
                                             const unsigned long long* __restrict__ keys_prev,
                                             float* __restrict__ h) {
    int idx = blockIdx.x * 256 + threadIdx.x;    // 0..65535
    int b = idx >> 7;
    int j4 = (idx & 127) << 2;
    int tok = SOS;
    if (keys_prev) tok = (VOCAB - 1) - (int)(uint32_t)(keys_prev[b] & 0xffffffffULL);
    const float* Pr = P + (size_t)tok * GIH;
    const float* Gr = Gh + (size_t)b * GIH;
    float4 ir = *(const float4*)&Pr[j4];
    float4 iz = *(const float4*)&Pr[j4 + HIDDEN];
    float4 in_ = *(const float4*)&Pr[j4 + 2 * HIDDEN];
    float4 hr = *(const float4*)&Gr[j4];
    float4 hz = *(const float4*)&Gr[j4 + HIDDEN];
    float4 hn = *(const float4*)&Gr[j4 + 2 * HIDDEN];
    float4 bir = *(const float4*)&bih[j4];
    float4 biz = *(const float4*)&bih[j4 + HIDDEN];
    float4 bin = *(const float4*)&bih[j4 + 2 * HIDDEN];
    float4 bhr = *(const float4*)&bhh[j4];
    float4 bhz = *(const float4*)&bhh[j4 + HIDDEN];
    float4 bhn = *(const float4*)&bhh[j4 + 2 * HIDDEN];
    float4 ho = *(const float4*)&h[(size_t)b * HIDDEN + j4];
    float irr[4] = {ir.x + bir.x, ir.y + bir.y, ir.z + bir.z, ir.w + bir.w};
    float izz[4] = {iz.x + biz.x, iz.y + biz.y, iz.z + biz.z, iz.w + biz.w};
    float inn[4] = {in_.x + bin.x, in_.y + bin.y, in_.z + bin.z, in_.w + bin.w};
    float hrr[4] = {hr.x + bhr.x, hr.y + bhr.y, hr.z + bhr.z, hr.w + bhr.w};
    float hzz[4] = {hz.x + bhz.x, hz.y + bhz.y, hz.z + bhz.z, hz.w + bhz.w};
    float hnn[4] = {hn.x + bhn.x, hn.y + bhn.y, hn.z + bhn.z, hn.w + bhn.w};
    float hov[4] = {ho.x, ho.y, ho.z, ho.w};
    float res[4];
#pragma unroll
    for (int i = 0; i < 4; ++i) {
        float r = 1.0f / (1.0f + expf(-(irr[i] + hrr[i])));
        float z = 1.0f / (1.0f + expf(-(izz[i] + hzz[i])));
        float n = tanhf(inn[i] + r * hnn[i]);
        res[i] = (1.0f - z) * n + z * hov[i];
    }
    *(float4*)&h[(size_t)b * HIDDEN + j4] = make_float4(res[0], res[1], res[2], res[3]);
}

// ---------------- logits + argmax (BM=64 x BN=128, 4x8 micro, dbuf)
__global__ __launch_bounds__(256) void k_logits(const float* __restrict__ h,
                                                const float* __restrict__ outW,
                                                const float* __restrict__ outb,
                                                const float* __restrict__ gum_t,
                                                unsigned long long* __restrict__ keys_t) {
    __shared__ __align__(16) float As[2][BK][BM + 4];
    __shared__ __align__(16) float Bs[2][BK][128 + 4];
    __shared__ unsigned long long red[BM][16];
    const int tid = threadIdx.x;
    const int arow = tid >> 2, ak = (tid & 3) << 2;
    const int tx = tid & 15, ty = tid >> 4;
    const int m0 = blockIdx.y * BM, n0 = blockIdx.x * 128;
    const float* Ap = h + (size_t)(m0 + arow) * HIDDEN;
    const float* Bp0 = outW + (size_t)(n0 + arow) * HIDDEN;
    const float* Bp1 = outW + (size_t)(n0 + 64 + arow) * HIDDEN;
    float4 aR = *(const float4*)&Ap[ak];
    float4 bR0 = *(const float4*)&Bp0[ak];
    float4 bR1 = *(const float4*)&Bp1[ak];
    float acc[4][8] = {};
    int buf = 0;
    for (int k0 = 0; k0 < HIDDEN; k0 += BK) {
        As[buf][ak+0][arow] = aR.x; As[buf][ak+1][arow] = aR.y;
        As[buf][ak+2][arow] = aR.z; As[buf][ak+3][arow] = aR.w;
        Bs[buf][ak+0][arow] = bR0.x; Bs[buf][ak+1][arow] = bR0.y;
        Bs[buf][ak+2][arow] = bR0.z; Bs[buf][ak+3][arow] = bR0.w;
        Bs[buf][ak+0][arow+64] = bR1.x; Bs[buf][ak+1][arow+64] = bR1.y;
        Bs[buf][ak+2][arow+64] = bR1.z; Bs[buf][ak+3][arow+64] = bR1.w;
        __syncthreads();
        if (k0 + BK < HIDDEN) {
            aR  = *(const float4*)&Ap[k0 + BK + ak];
            bR0 = *(const float4*)&Bp0[k0 + BK + ak];
            bR1 = *(const float4*)&Bp1[k0 + BK + ak];
        }
#pragma unroll
        for (int kk = 0; kk < BK; ++kk) {
            float4 av  = *(const float4*)&As[buf][kk][ty * 4];
            float4 bv0 = *(const float4*)&Bs[buf][kk][tx * 4];
            float4 bv1 = *(const float4*)&Bs[buf][kk][64 + tx * 4];
            float ar[4] = {av.x, av.y, av.z, av.w};
            float br[8] = {bv0.x, bv0.y, bv0.z, bv0.w, bv1.x, bv1.y, bv1.z, bv1.w};
#pragma unroll
            for (int i = 0; i < 4; ++i)
#pragma unroll
                for (int j = 0; j < 8; ++j) acc[i][j] += ar[i] * br[j];
        }
        buf ^= 1;
    }
    float4 ob0 = *(const float4*)&outb[n0 + tx * 4];
    float4 ob1 = *(const float4*)&outb[n0 + 64 + tx * 4];
    float obr[8] = {ob0.x, ob0.y, ob0.z, ob0.w, ob1.x, ob1.y, ob1.z, ob1.w};
#pragma unroll
    for (int i = 0; i < 4; ++i) {
        int r = m0 + ty * 4 + i;
        float4 g0 = *(const float4*)&gum_t[(size_t)r * VOCAB + n0 + tx * 4];
        float4 g1 = *(const float4*)&gum_t[(size_t)r * VOCAB + n0 + 64 + tx * 4];
        float gr[8] = {g0.x, g0.y, g0.z, g0.w, g1.x, g1.y, g1.z, g1.w};
        unsigned long long best = 0ULL;
#pragma unroll
        for (int j = 0; j < 8; ++j) {
            int c = n0 + ((j < 4) ? (tx * 4 + j) : (64 + tx * 4 + j - 4));
            float v = acc[i][j] + obr[j] + gr[j];
            unsigned long long key = pack_key(v, c);
            if (key > best) best = key;
        }
        red[ty * 4 + i][tx] = best;
    }
    __syncthreads();
    if (tid < BM) {
        unsigned long long best = red[tid][0];
#pragma unroll
        for (int q = 1; q < 16; ++q)
            if (red[tid][q] > best) best = red[tid][q];
        atomicMax(&keys_t[m0 + tid], best);
    }
}

// ---------------- finalize
__global__ __launch_bounds__(256) void k_final(const unsigned long long* __restrict__ keys,
                                               float* __restrict__ out) {
    int b = blockIdx.x * 256 + threadIdx.x;
    if (b >= BATCH) return;
    int toks[TSTEPS];
    int len = 1;
    bool done = false;
#pragma unroll
    for (int t = 0; t < TSTEPS; ++t) {
        int tok = (VOCAB - 1) - (int)(uint32_t)(keys[(size_t)t * BATCH + b] & 0xffffffffULL);
        toks[t] = tok;
        if (!done) len++;
        if (tok == EOS) done = true;
    }
    if (!done) len++;
    float* lang = out + (size_t)b * MAXLEN * VOCAB;
    lang[SOS] = 1.0f;
#pragma unroll
    for (int t = 0; t < TSTEPS; ++t) {
        int pos = t + 1;
        if (pos < len) lang[(size_t)pos * VOCAB + toks[t]] = 1.0f;
    }
    if (len == MAXLEN) lang[(size_t)(MAXLEN - 1) * VOCAB + EOS] = 1.0f;
    out[(size_t)BATCH * MAXLEN * VOCAB + b] = (float)len;
    if (b == 0) out[(size_t)BATCH * MAXLEN * VOCAB + BATCH] = 0.0f;
}

extern "C" void kernel_launch(void* const* d_in, const int* in_sizes, int n_in,
                              void* d_out, int out_size, void* d_ws, size_t ws_size,
                              hipStream_t stream) {
    const float* feats = (const float*)d_in[0];
    const int*   targets = (const int*)d_in[1];
    const float* featW = (const float*)d_in[2];
    const float* featb = (const float*)d_in[3];
    const float* embW  = (const float*)d_in[4];
    const float* initW = (const float*)d_in[5];
    const float* initb = (const float*)d_in[6];
    const float* Wih   = (const float*)d_in[7];
    const float* bih   = (const float*)d_in[9];
    const float* Whh   = (const float*)d_in[8];
    const float* bhh   = (const float*)d_in[10];
    const float* outW  = (const float*)d_in[11];
    const float* outb  = (const float*)d_in[12];
    const float* gumbel = (const float*)d_in[13];
    float* out = (float*)d_out;

    char* ws = (char*)d_ws;
    float* h  = (float*)(ws);                                    // 1 MB
    float* Gh = (float*)(ws + (1 << 20));                        // 3 MB
    float* fe = (float*)(ws + 4 * (1 << 20));                    // 3 MB
    unsigned long long* keys = (unsigned long long*)(ws + 7 * (1 << 20));  // 152 KB
    float* P  = (float*)(ws + 8 * (1 << 20));                    // 25.2 MB

    int zb = (out_size / 4 + 256) / 256;
    k_zero<<<dim3(zb), 256, 0, stream>>>(out, out_size, keys);

    k_fe<<<dim3(FEATSZ / BM, (BATCH * NOBJ) / BM), 256, 0, stream>>>(feats, featW, featb, fe);
    k_h0<<<dim3(HIDDEN / BM, BATCH / BM), 256, 0, stream>>>(fe, initW, initb, targets, h);
    k_P<<<dim3(GIH / 128, VOCAB / BM), 256, 0, stream>>>(embW, Wih, P);

    for (int t = 0; t < TSTEPS; ++t) {
        const unsigned long long* kprev = (t == 0) ? nullptr : (keys + (size_t)(t - 1) * BATCH);
        k_gatesH<<<dim3(GIH / BM, BATCH / BM), 256, 0, stream>>>(h, Whh, Gh);
        k_gru<<<dim3(BATCH * HIDDEN / 4 / 256), 256, 0, stream>>>(Gh, P, bih, bhh, kprev, h);
        k_logits<<<dim3(VOCAB / 128, BATCH / BM), 256, 0, stream>>>(
            h, outW, outb, gumbel + (size_t)t * BATCH * VOCAB, keys + (size_t)t * BATCH);
    }
    k_final<<<dim3(2), 256, 0, stream>>>(keys, out);
}

// Round 4
// 2655.572 us; speedup vs baseline: 1.6712x; 1.2067x over previous
//
#include <hip/hip_runtime.h>
#include <cstdint>
#include <cstddef>

#define BATCH   512
#define HIDDEN  512
#define EMB     512
#define VOCAB   4096
#define NOBJ    3
#define FEATIN  2048
#define FEATSZ  512
#define MAXLEN  40
#define TSTEPS  38
#define SOS     1
#define EOS     2
#define GIH     1536   // 3*HIDDEN
#define KCH     256    // split-K chunk for gatesH (HIDDEN/2)

#define BK 16
#define BM 64

#define NLOGITS_BLK 512                   // 64 n-tiles x 8 m-tiles
#define NGATES_BLK  384                   // 24 n-tiles x 8 m-tiles x 2 kc
#define NCOMB_BLK   (NLOGITS_BLK + NGATES_BLK)

static __device__ __forceinline__ unsigned long long pack_key(float v, int col) {
    uint32_t u = __float_as_uint(v);
    u = (u & 0x80000000u) ? ~u : (u | 0x80000000u);   // order-preserving map
    return ((unsigned long long)u << 32) | (uint32_t)(VOCAB - 1 - col);  // low col wins ties
}

// ---------------- zero d_out + keys
__global__ __launch_bounds__(256) void k_zero(float* __restrict__ out, int n,
                                              unsigned long long* __restrict__ keys) {
    int tid = threadIdx.x;
    size_t base = (size_t)blockIdx.x * 4096;
#pragma unroll
    for (int s = 0; s < 4; ++s) {
        size_t i4 = base + (size_t)s * 1024 + (size_t)tid * 4;
        if (i4 + 3 < (size_t)n) {
            *(float4*)&out[i4] = make_float4(0.f, 0.f, 0.f, 0.f);
        } else {
            for (size_t j = i4; j < (size_t)n; ++j) out[j] = 0.f;
        }
    }
    size_t gi = (size_t)blockIdx.x * 256 + tid;
    if (gi < (size_t)TSTEPS * BATCH) keys[gi] = 0ULL;
}

// ---------------- feature embed (one-time): fe[1536,512] = feats @ featW^T + featb
__global__ __launch_bounds__(256) void k_fe(const float* __restrict__ feats,
                                            const float* __restrict__ featW,
                                            const float* __restrict__ featb,
                                            float* __restrict__ fe) {
    __shared__ float As[BK][BM];
    __shared__ float Bs[BK][BM];
    const int tid = threadIdx.x;
    const int m0 = blockIdx.y * BM, n0 = blockIdx.x * BM;
    const int tx = tid & 15, ty = tid >> 4;
    const int lrow = tid >> 2, lk = (tid & 3) << 2;
    float acc[4][4] = {};
    for (int k0 = 0; k0 < FEATIN; k0 += BK) {
        float4 a = *(const float4*)&feats[(size_t)(m0 + lrow) * FEATIN + k0 + lk];
        float4 b = *(const float4*)&featW[(size_t)(n0 + lrow) * FEATIN + k0 + lk];
        __syncthreads();
        As[lk+0][lrow] = a.x; As[lk+1][lrow] = a.y; As[lk+2][lrow] = a.z; As[lk+3][lrow] = a.w;
        Bs[lk+0][lrow] = b.x; Bs[lk+1][lrow] = b.y; Bs[lk+2][lrow] = b.z; Bs[lk+3][lrow] = b.w;
        __syncthreads();
#pragma unroll
        for (int kk = 0; kk < BK; ++kk) {
            float4 av = *(const float4*)&As[kk][ty * 4];
            float4 bv = *(const float4*)&Bs[kk][tx * 4];
            float ar[4] = {av.x, av.y, av.z, av.w};
            float br[4] = {bv.x, bv.y, bv.z, bv.w};
#pragma unroll
            for (int i = 0; i < 4; ++i)
#pragma unroll
                for (int j = 0; j < 4; ++j) acc[i][j] += ar[i] * br[j];
        }
    }
#pragma unroll
    for (int i = 0; i < 4; ++i) {
        int r = m0 + ty * 4 + i;
#pragma unroll
        for (int j = 0; j < 4; ++j) {
            int c = n0 + tx * 4 + j;
            fe[(size_t)r * FEATSZ + c] = acc[i][j] + featb[c];
        }
    }
}

// ---------------- h0 (one-time): h0 = ft[512,1539] @ initW^T + initb
__global__ __launch_bounds__(256) void k_h0(const float* __restrict__ fe,
                                            const float* __restrict__ initW,
                                            const float* __restrict__ initb,
                                            const int* __restrict__ targets,
                                            float* __restrict__ h) {
    __shared__ float As[BK][BM];
    __shared__ float Bs[BK][BM];
    const int tid = threadIdx.x;
    const int m0 = blockIdx.y * BM, n0 = blockIdx.x * BM;
    const int tx = tid & 15, ty = tid >> 4;
    const int lrow = tid >> 2, lk = (tid & 3) << 2;
    float acc[4][4] = {};
    const int K = NOBJ * FEATSZ;  // 1536
    for (int k0 = 0; k0 < K; k0 += BK) {
        float4 a = *(const float4*)&fe[(size_t)(m0 + lrow) * K + k0 + lk];
        float breg[4];
#pragma unroll
        for (int i = 0; i < 4; ++i) {
            int ka = k0 + lk + i;
            breg[i] = initW[(size_t)(n0 + lrow) * 1539 + ka + (ka >> 9)];
        }
        __syncthreads();
        As[lk+0][lrow] = a.x; As[lk+1][lrow] = a.y; As[lk+2][lrow] = a.z; As[lk+3][lrow] = a.w;
#pragma unroll
        for (int i = 0; i < 4; ++i) Bs[lk + i][lrow] = breg[i];
        __syncthreads();
#pragma unroll
        for (int kk = 0; kk < BK; ++kk) {
            float4 av = *(const float4*)&As[kk][ty * 4];
            float4 bv = *(const float4*)&Bs[kk][tx * 4];
            float ar[4] = {av.x, av.y, av.z, av.w};
            float br[4] = {bv.x, bv.y, bv.z, bv.w};
#pragma unroll
            for (int i = 0; i < 4; ++i)
#pragma unroll
                for (int j = 0; j < 4; ++j) acc[i][j] += ar[i] * br[j];
        }
    }
#pragma unroll
    for (int i = 0; i < 4; ++i) {
        int r = m0 + ty * 4 + i;
        int tg = targets[r];
#pragma unroll
        for (int j = 0; j < 4; ++j) {
            int c = n0 + tx * 4 + j;
            h[(size_t)r * HIDDEN + c] =
                acc[i][j] + initb[c] + initW[(size_t)c * 1539 + tg * 513 + 512];
        }
    }
}

// ---------------- P[4096,1536] = embW @ Wih^T + bih (one-time; bih folded)
__global__ __launch_bounds__(256) void k_P(const float* __restrict__ embW,
                                           const float* __restrict__ Wih,
                                           const float* __restrict__ bih,
                                           float* __restrict__ P) {
    __shared__ __align__(16) float As[2][BK][BM + 4];
    __shared__ __align__(16) float Bs[2][BK][128 + 4];
    const int tid = threadIdx.x;
    const int arow = tid >> 2, ak = (tid & 3) << 2;
    const int tx = tid & 15, ty = tid >> 4;
    const int m0 = blockIdx.y * BM, n0 = blockIdx.x * 128;
    const float* Ap = embW + (size_t)(m0 + arow) * EMB;
    const float* Bp0 = Wih + (size_t)(n0 + arow) * EMB;
    const float* Bp1 = Wih + (size_t)(n0 + 64 + arow) * EMB;
    float4 aR = *(const float4*)&Ap[ak];
    float4 bR0 = *(const float4*)&Bp0[ak];
    float4 bR1 = *(const float4*)&Bp1[ak];
    float acc[4][8] = {};
    int buf = 0;
    for (int k0 = 0; k0 < EMB; k0 += BK) {
        As[buf][ak+0][arow] = aR.x; As[buf][ak+1][arow] = aR.y;
        As[buf][ak+2][arow] = aR.z; As[buf][ak+3][arow] = aR.w;
        Bs[buf][ak+0][arow] = bR0.x; Bs[buf][ak+1][arow] = bR0.y;
        Bs[buf][ak+2][arow] = bR0.z; Bs[buf][ak+3][arow] = bR0.w;
        Bs[buf][ak+0][arow+64] = bR1.x; Bs[buf][ak+1][arow+64] = bR1.y;
        Bs[buf][ak+2][arow+64] = bR1.z; Bs[buf][ak+3][arow+64] = bR1.w;
        __syncthreads();
        if (k0 + BK < EMB) {
            aR  = *(const float4*)&Ap[k0 + BK + ak];
            bR0 = *(const float4*)&Bp0[k0 + BK + ak];
            bR1 = *(const float4*)&Bp1[k0 + BK + ak];
        }
#pragma unroll
        for (int kk = 0; kk < BK; ++kk) {
            float4 av  = *(const float4*)&As[buf][kk][ty * 4];
            float4 bv0 = *(const float4*)&Bs[buf][kk][tx * 4];
            float4 bv1 = *(const float4*)&Bs[buf][kk][64 + tx * 4];
            float ar[4] = {av.x, av.y, av.z, av.w};
            float br[8] = {bv0.x, bv0.y, bv0.z, bv0.w, bv1.x, bv1.y, bv1.z, bv1.w};
#pragma unroll
            for (int i = 0; i < 4; ++i)
#pragma unroll
                for (int j = 0; j < 8; ++j) acc[i][j] += ar[i] * br[j];
        }
        buf ^= 1;
    }
    float4 bi0 = *(const float4*)&bih[n0 + tx * 4];
    float4 bi1 = *(const float4*)&bih[n0 + 64 + tx * 4];
#pragma unroll
    for (int i = 0; i < 4; ++i) {
        int r = m0 + ty * 4 + i;
        *(float4*)&P[(size_t)r * GIH + n0 + tx * 4] =
            make_float4(acc[i][0] + bi0.x, acc[i][1] + bi0.y, acc[i][2] + bi0.z, acc[i][3] + bi0.w);
        *(float4*)&P[(size_t)r * GIH + n0 + 64 + tx * 4] =
            make_float4(acc[i][4] + bi1.x, acc[i][5] + bi1.y, acc[i][6] + bi1.z, acc[i][7] + bi1.w);
    }
}

// ---------------- combined: logits(t) [blocks 0..511] + gatesH(t+1) split-K [blocks 512..895]
__global__ __launch_bounds__(256) void k_comb(const float* __restrict__ h,
                                              const float* __restrict__ Whh,
                                              float* __restrict__ Gp,
                                              const float* __restrict__ outW,
                                              const float* __restrict__ outb,
                                              const float* __restrict__ gum_t,
                                              unsigned long long* __restrict__ keys_t,
                                              int do_logits, int do_gates) {
    __shared__ __align__(16) float As[2][BK][BM + 4];
    __shared__ __align__(16) float Bs[2][BK][BM + 4];
    __shared__ unsigned long long red[BM][16];
    const int tid = threadIdx.x;
    const int arow = tid >> 2, ak = (tid & 3) << 2;
    const int tx = tid & 15, ty = tid >> 4;
    const int bx = blockIdx.x;

    if (bx < NLOGITS_BLK) {
        // ---------- logits job: 64x64 tile over K=512
        if (!do_logits) return;
        const int n0 = (bx & 63) * 64, m0 = (bx >> 6) * 64;
        const float* Ap = h + (size_t)(m0 + arow) * HIDDEN;
        const float* Bp = outW + (size_t)(n0 + arow) * HIDDEN;
        float4 aR = *(const float4*)&Ap[ak];
        float4 bR = *(const float4*)&Bp[ak];
        float acc[4][4] = {};
        int buf = 0;
        for (int k0 = 0; k0 < HIDDEN; k0 += BK) {
            As[buf][ak+0][arow] = aR.x; As[buf][ak+1][arow] = aR.y;
            As[buf][ak+2][arow] = aR.z; As[buf][ak+3][arow] = aR.w;
            Bs[buf][ak+0][arow] = bR.x; Bs[buf][ak+1][arow] = bR.y;
            Bs[buf][ak+2][arow] = bR.z; Bs[buf][ak+3][arow] = bR.w;
            __syncthreads();
            if (k0 + BK < HIDDEN) {
                aR = *(const float4*)&Ap[k0 + BK + ak];
                bR = *(const float4*)&Bp[k0 + BK + ak];
            }
#pragma unroll
            for (int kk = 0; kk < BK; ++kk) {
                float4 av = *(const float4*)&As[buf][kk][ty * 4];
                float4 bv = *(const float4*)&Bs[buf][kk][tx * 4];
                float ar[4] = {av.x, av.y, av.z, av.w};
                float br[4] = {bv.x, bv.y, bv.z, bv.w};
#pragma unroll
                for (int i = 0; i < 4; ++i)
#pragma unroll
                    for (int j = 0; j < 4; ++j) acc[i][j] += ar[i] * br[j];
            }
            buf ^= 1;
        }
        float4 ob = *(const float4*)&outb[n0 + tx * 4];
        float obr[4] = {ob.x, ob.y, ob.z, ob.w};
#pragma unroll
        for (int i = 0; i < 4; ++i) {
            int r = m0 + ty * 4 + i;
            float4 g = *(const float4*)&gum_t[(size_t)r * VOCAB + n0 + tx * 4];
            float gr[4] = {g.x, g.y, g.z, g.w};
            unsigned long long best = 0ULL;
#pragma unroll
            for (int j = 0; j < 4; ++j) {
                int c = n0 + tx * 4 + j;
                unsigned long long key = pack_key(acc[i][j] + obr[j] + gr[j], c);
                if (key > best) best = key;
            }
            red[ty * 4 + i][tx] = best;
        }
        __syncthreads();
        if (tid < BM) {
            unsigned long long best = red[tid][0];
#pragma unroll
            for (int q = 1; q < 16; ++q)
                if (red[tid][q] > best) best = red[tid][q];
            atomicMax(&keys_t[m0 + tid], best);
        }
    } else {
        // ---------- gatesH job: Gp[kc][512,1536] partial = h[:,kcK] @ Whh[:,kcK]^T
        if (!do_gates) return;
        const int gx = bx - NLOGITS_BLK;          // 0..383
        const int jn = gx % 24;                   // n-tile
        const int rest = gx / 24;                 // 0..15
        const int jm = rest & 7, kc = rest >> 3;  // m-tile, K-chunk
        const int m0 = jm * 64, n0 = jn * 64;
        const float* Ap = h + (size_t)(m0 + arow) * HIDDEN + kc * KCH;
        const float* Bp = Whh + (size_t)(n0 + arow) * HIDDEN + kc * KCH;
        float4 aR = *(const float4*)&Ap[ak];
        float4 bR = *(const float4*)&Bp[ak];
        float acc[4][4] = {};
        int buf = 0;
        for (int k0 = 0; k0 < KCH; k0 += BK) {
            As[buf][ak+0][arow] = aR.x; As[buf][ak+1][arow] = aR.y;
            As[buf][ak+2][arow] = aR.z; As[buf][ak+3][arow] = aR.w;
            Bs[buf][ak+0][arow] = bR.x; Bs[buf][ak+1][arow] = bR.y;
            Bs[buf][ak+2][arow] = bR.z; Bs[buf][ak+3][arow] = bR.w;
            __syncthreads();
            if (k0 + BK < KCH) {
                aR = *(const float4*)&Ap[k0 + BK + ak];
                bR = *(const float4*)&Bp[k0 + BK + ak];
            }
#pragma unroll
            for (int kk = 0; kk < BK; ++kk) {
                float4 av = *(const float4*)&As[buf][kk][ty * 4];
                float4 bv = *(const float4*)&Bs[buf][kk][tx * 4];
                float ar[4] = {av.x, av.y, av.z, av.w};
                float br[4] = {bv.x, bv.y, bv.z, bv.w};
#pragma unroll
                for (int i = 0; i < 4; ++i)
#pragma unroll
                    for (int j = 0; j < 4; ++j) acc[i][j] += ar[i] * br[j];
            }
            buf ^= 1;
        }
        float* Go = Gp + (size_t)(kc * BATCH) * GIH;
#pragma unroll
        for (int i = 0; i < 4; ++i) {
            int r = m0 + ty * 4 + i;
            *(float4*)&Go[(size_t)r * GIH + n0 + tx * 4] =
                make_float4(acc[i][0], acc[i][1], acc[i][2], acc[i][3]);
        }
    }
}

// ---------------- GRU elementwise: h = (1-z)*n + z*h  (sums 2 Gp partials; bih in P)
__global__ __launch_bounds__(256) void k_gru(const float* __restrict__ Gp,
                                             const float* __restrict__ P,
                                             const float* __restrict__ bhh,
                                             const unsigned long long* __restrict__ keys_prev,
                                             float* __restrict__ h) {
    int idx = blockIdx.x * 256 + threadIdx.x;    // 0..65535
    int b = idx >> 7;
    int j4 = (idx & 127) << 2;
    int tok = SOS;
    if (keys_prev) tok = (VOCAB - 1) - (int)(uint32_t)(keys_prev[b] & 0xffffffffULL);
    const float* Pr = P + (size_t)tok * GIH;
    const float* G0 = Gp + (size_t)b * GIH;
    const float* G1 = Gp + (size_t)(BATCH + b) * GIH;
    float4 ir = *(const float4*)&Pr[j4];
    float4 iz = *(const float4*)&Pr[j4 + HIDDEN];
    float4 in_ = *(const float4*)&Pr[j4 + 2 * HIDDEN];
    float4 hr0 = *(const float4*)&G0[j4];
    float4 hz0 = *(const float4*)&G0[j4 + HIDDEN];
    float4 hn0 = *(const float4*)&G0[j4 + 2 * HIDDEN];
    float4 hr1 = *(const float4*)&G1[j4];
    float4 hz1 = *(const float4*)&G1[j4 + HIDDEN];
    float4 hn1 = *(const float4*)&G1[j4 + 2 * HIDDEN];
    float4 bhr = *(const float4*)&bhh[j4];
    float4 bhz = *(const float4*)&bhh[j4 + HIDDEN];
    float4 bhn = *(const float4*)&bhh[j4 + 2 * HIDDEN];
    float4 ho = *(const float4*)&h[(size_t)b * HIDDEN + j4];
    float irr[4] = {ir.x, ir.y, ir.z, ir.w};
    float izz[4] = {iz.x, iz.y, iz.z, iz.w};
    float inn[4] = {in_.x, in_.y, in_.z, in_.w};
    float hrr[4] = {hr0.x + hr1.x + bhr.x, hr0.y + hr1.y + bhr.y,
                    hr0.z + hr1.z + bhr.z, hr0.w + hr1.w + bhr.w};
    float hzz[4] = {hz0.x + hz1.x + bhz.x, hz0.y + hz1.y + bhz.y,
                    hz0.z + hz1.z + bhz.z, hz0.w + hz1.w + bhz.w};
    float hnn[4] = {hn0.x + hn1.x + bhn.x, hn0.y + hn1.y + bhn.y,
                    hn0.z + hn1.z + bhn.z, hn0.w + hn1.w + bhn.w};
    float hov[4] = {ho.x, ho.y, ho.z, ho.w};
    float res[4];
#pragma unroll
    for (int i = 0; i < 4; ++i) {
        float r = 1.0f / (1.0f + expf(-(irr[i] + hrr[i])));
        float z = 1.0f / (1.0f + expf(-(izz[i] + hzz[i])));
        float n = tanhf(inn[i] + r * hnn[i]);
        res[i] = (1.0f - z) * n + z * hov[i];
    }
    *(float4*)&h[(size_t)b * HIDDEN + j4] = make_float4(res[0], res[1], res[2], res[3]);
}

// ---------------- finalize
__global__ __launch_bounds__(256) void k_final(const unsigned long long* __restrict__ keys,
                                               float* __restrict__ out) {
    int b = blockIdx.x * 256 + threadIdx.x;
    if (b >= BATCH) return;
    int toks[TSTEPS];
    int len = 1;
    bool done = false;
#pragma unroll
    for (int t = 0; t < TSTEPS; ++t) {
        int tok = (VOCAB - 1) - (int)(uint32_t)(keys[(size_t)t * BATCH + b] & 0xffffffffULL);
        toks[t] = tok;
        if (!done) len++;
        if (tok == EOS) done = true;
    }
    if (!done) len++;
    float* lang = out + (size_t)b * MAXLEN * VOCAB;
    lang[SOS] = 1.0f;
#pragma unroll
    for (int t = 0; t < TSTEPS; ++t) {
        int pos = t + 1;
        if (pos < len) lang[(size_t)pos * VOCAB + toks[t]] = 1.0f;
    }
    if (len == MAXLEN) lang[(size_t)(MAXLEN - 1) * VOCAB + EOS] = 1.0f;
    out[(size_t)BATCH * MAXLEN * VOCAB + b] = (float)len;
    if (b == 0) out[(size_t)BATCH * MAXLEN * VOCAB + BATCH] = 0.0f;
}

extern "C" void kernel_launch(void* const* d_in, const int* in_sizes, int n_in,
                              void* d_out, int out_size, void* d_ws, size_t ws_size,
                              hipStream_t stream) {
    const float* feats = (const float*)d_in[0];
    const int*   targets = (const int*)d_in[1];
    const float* featW = (const float*)d_in[2];
    const float* featb = (const float*)d_in[3];
    const float* embW  = (const float*)d_in[4];
    const float* initW = (const float*)d_in[5];
    const float* initb = (const float*)d_in[6];
    const float* Wih   = (const float*)d_in[7];
    const float* Whh   = (const float*)d_in[8];
    const float* bih   = (const float*)d_in[9];
    const float* bhh   = (const float*)d_in[10];
    const float* outW  = (const float*)d_in[11];
    const float* outb  = (const float*)d_in[12];
    const float* gumbel = (const float*)d_in[13];
    float* out = (float*)d_out;

    // workspace layout (<= 33.2 MB, known-good budget):
    char* ws = (char*)d_ws;
    float* h  = (float*)(ws);                                    // 1 MB
    unsigned long long* keys = (unsigned long long*)(ws + (1 << 20));  // 152 KB
    float* Gp = (float*)(ws + 5 * (1 << 18));                    // @1.25 MB: 2x512x1536x4 = 6.29 MB
    float* fe = Gp;                                              // alias: fe (3 MB) dead before Gp use
    float* P  = (float*)(ws + 8 * (1 << 20));                    // @8 MB: 25.17 MB

    int zb = (out_size + 4095) / 4096;
    k_zero<<<dim3(zb), 256, 0, stream>>>(out, out_size, keys);

    k_fe<<<dim3(FEATSZ / BM, (BATCH * NOBJ) / BM), 256, 0, stream>>>(feats, featW, featb, fe);
    k_h0<<<dim3(HIDDEN / BM, BATCH / BM), 256, 0, stream>>>(fe, initW, initb, targets, h);
    k_P<<<dim3(GIH / 128, VOCAB / BM), 256, 0, stream>>>(embW, Wih, bih, P);

    // prime gatesH(0) from h0 (logits blocks exit early)
    k_comb<<<dim3(NCOMB_BLK), 256, 0, stream>>>(h, Whh, Gp, outW, outb, gumbel, keys, 0, 1);

    for (int t = 0; t < TSTEPS; ++t) {
        const unsigned long long* kprev = (t == 0) ? nullptr : (keys + (size_t)(t - 1) * BATCH);
        k_gru<<<dim3(BATCH * HIDDEN / 4 / 256), 256, 0, stream>>>(Gp, P, bhh, kprev, h);
        k_comb<<<dim3(NCOMB_BLK), 256, 0, stream>>>(
            h, Whh, Gp, outW, outb, gumbel + (size_t)t * BATCH * VOCAB,
            keys + (size_t)t * BATCH, 1, (t < TSTEPS - 1) ? 1 : 0);
    }
    k_final<<<dim3(2), 256, 0, stream>>>(keys, out);
}